// Round 1
// baseline (759.712 us; speedup 1.0000x reference)
//
#include <hip/hip_runtime.h>

#define IH 1024
#define IW 1024
#define TS 20          // time steps (baked; input time_steps == 20)
#define BT 64          // output tile
#define HXW 32         // x halo
#define HYW 20         // y halo
#define RX 128         // BT + 2*HXW
#define RY 104         // BT + 2*HYW
#define GX 136         // RX + 8 (4 pad each side -> interior 16B aligned)
#define GY 106         // RY + 2 ghost rows
#define NT 256

__global__ __launch_bounds__(NT, 1)
void inpaint20(const float* __restrict__ x, const float* __restrict__ wgt,
               float* __restrict__ out) {
  __shared__ float bufA[GY][GX];
  __shared__ float bufB[GY][GX];
  __shared__ unsigned char msk[RY][RX];

  const int tid  = threadIdx.x;
  const int bid  = blockIdx.x;
  const int img  = bid >> 8;          // 0..15  (B*C)
  const int tile = bid & 255;         // 16x16 tiles
  const int ty   = (tile >> 4) * BT;
  const int tx   = (tile & 15) * BT;
  const int ch   = img & 1;

  const float* __restrict__ xin = x + (size_t)img * (IH * IW);

  // 5-point stencil weights (corners of the 3x3 are exactly 0.0)
  const float wN = wgt[ch * 9 + 1];
  const float wW = wgt[ch * 9 + 3];
  const float wC = wgt[ch * 9 + 4];
  const float wE = wgt[ch * 9 + 5];
  const float wS = wgt[ch * 9 + 7];

  // ---- global -> LDS (reflect-mapped), build mask bytes ----
  for (int i = tid; i < GY * GX; i += NT) {
    const int lr = i / GX;
    const int lc = i - lr * GX;
    int gr = ty - (HYW + 1) + lr;
    int gc = tx - (HXW + 4) + lc;
    gr = gr < 0 ? -gr : (gr >= IH ? 2 * IH - 2 - gr : gr);
    gc = gc < 0 ? -gc : (gc >= IW ? 2 * IW - 2 - gc : gc);
    const float v = xin[gr * IW + gc];
    bufA[lr][lc] = v;
    bufB[lr][lc] = v;
    if (lr >= 1 && lr <= RY && lc >= 4 && lc < 4 + RX)
      msk[lr - 1][lc - 4] = (v == 0.0f) ? 0xFFu : 0x00u;
  }
  __syncthreads();

  // thread -> work mapping: 16 x-groups of 8 cols, 16 row bands
  const int xg     = tid & 15;
  const int band   = tid >> 4;
  const int nrows  = (band < 8) ? 7 : 6;               // 8*7 + 8*6 = 104
  const int rstart = (band < 8) ? band * 7 : 56 + (band - 8) * 6;
  const int lc0    = 4 + xg * 8;                       // LDS col (16B aligned)

  // mask is static across steps: cache this thread's bytes in registers
  unsigned int m0[7], m1[7];
#pragma unroll
  for (int i = 0; i < 7; ++i) {
    int rr = rstart + i;
    rr = rr > RY - 1 ? RY - 1 : rr;
    const unsigned int* mp = (const unsigned int*)&msk[rr][xg * 8];
    m0[i] = mp[0];
    m1[i] = mp[1];
  }

  auto step = [&](const float (&cu)[GY][GX], float (&nx)[GY][GX]) {
    const float* cp = &cu[1 + rstart][lc0];
    float*       np = &nx[1 + rstart][lc0];
    float nn[8], cc[8], ss[8];
    {
      const float4 a = *(const float4*)(cp - GX);
      const float4 b = *(const float4*)(cp - GX + 4);
      nn[0]=a.x; nn[1]=a.y; nn[2]=a.z; nn[3]=a.w;
      nn[4]=b.x; nn[5]=b.y; nn[6]=b.z; nn[7]=b.w;
      const float4 c_ = *(const float4*)(cp);
      const float4 d_ = *(const float4*)(cp + 4);
      cc[0]=c_.x; cc[1]=c_.y; cc[2]=c_.z; cc[3]=c_.w;
      cc[4]=d_.x; cc[5]=d_.y; cc[6]=d_.z; cc[7]=d_.w;
    }
#pragma unroll
    for (int i = 0; i < 7; ++i) {
      if (i < nrows) {                       // wave-uniform (4 bands/wave)
        const float cl = cp[i * GX - 1];
        const float cr = cp[i * GX + 8];
        const float4 a = *(const float4*)(cp + (i + 1) * GX);
        const float4 b = *(const float4*)(cp + (i + 1) * GX + 4);
        ss[0]=a.x; ss[1]=a.y; ss[2]=a.z; ss[3]=a.w;
        ss[4]=b.x; ss[5]=b.y; ss[6]=b.z; ss[7]=b.w;
        float ov[8];
#pragma unroll
        for (int j = 0; j < 8; ++j) {
          const float l = (j == 0) ? cl : cc[j - 1];
          const float r = (j == 7) ? cr : cc[j + 1];
          const float cv = fmaf(wC, cc[j],
                           fmaf(wW, l,
                           fmaf(wE, r,
                           fmaf(wN, nn[j], wS * ss[j]))));
          const unsigned int mw = (j < 4) ? m0[i] : m1[i];
          const int sh = j & 3;
          const int mm = (int)(mw << ((3 - sh) * 8)) >> 24;  // sext byte -> 0 / -1
          const unsigned int rb = (__float_as_uint(cv) & (unsigned int)mm)
                                | (__float_as_uint(cc[j]) & ~(unsigned int)mm);
          ov[j] = __uint_as_float(rb);       // exact select: conv if hole else frozen x
        }
        float4 o0, o1;
        o0.x=ov[0]; o0.y=ov[1]; o0.z=ov[2]; o0.w=ov[3];
        o1.x=ov[4]; o1.y=ov[5]; o1.z=ov[6]; o1.w=ov[7];
        *(float4*)(np + i * GX)     = o0;
        *(float4*)(np + i * GX + 4) = o1;
#pragma unroll
        for (int j = 0; j < 8; ++j) { nn[j] = cc[j]; cc[j] = ss[j]; }
      }
    }
  };

#pragma unroll 1
  for (int s = 0; s < TS; s += 2) {
    step(bufA, bufB);
    __syncthreads();
    step(bufB, bufA);
    __syncthreads();
  }

  // ---- store tile (result ends in bufA after an even number of steps) ----
  float* __restrict__ op = out + (size_t)img * (IH * IW);
  for (int i = tid; i < BT * BT; i += NT) {
    const int r = i >> 6;
    const int c = i & 63;
    op[(ty + r) * IW + (tx + c)] = bufA[HYW + 1 + r][HXW + 4 + c];
  }
}

extern "C" void kernel_launch(void* const* d_in, const int* in_sizes, int n_in,
                              void* d_out, int out_size, void* d_ws, size_t ws_size,
                              hipStream_t stream) {
  (void)in_sizes; (void)n_in; (void)d_ws; (void)ws_size; (void)out_size;
  const float* x   = (const float*)d_in[0];
  const float* wgt = (const float*)d_in[1];
  float* out       = (float*)d_out;
  // grid: 16 images (B*C) x 256 tiles (16x16) each
  hipLaunchKernelGGL(inpaint20, dim3(4096), dim3(NT), 0, stream, x, wgt, out);
}

// Round 2
// 521.094 us; speedup vs baseline: 1.4579x; 1.4579x over previous
//
#include <hip/hip_runtime.h>

#define IH 1024
#define IW 1024
#define TS 20          // time steps (baked; input time_steps == 20)
#define BT 64          // output tile
#define HXW 32         // x halo
#define HYW 20         // y halo
#define RX 128         // BT + 2*HXW
#define RY 104         // BT + 2*HYW
#define GX 136         // RX + 8 (4 pad each side -> interior granule-aligned)
#define GY 106         // RY + 2 ghost rows
#define NDW 14432      // GY*GX = 14416, rounded up to multiple of 32 dwords (128B)
#define NT 512

// 16B-granule XOR swizzle. (r>>3)^r spreads rows that differ by 4 AND by 8
// (a wave's 4 bands are 3-4 rows apart; plain r&7 would alias rows 8 apart).
__device__ __forceinline__ int swz(int r, int c) {
  return (r * GX + c) ^ ((((r >> 3) ^ r) & 7) << 2);
}

__global__ __launch_bounds__(NT, 1)
void inpaint20(const float* __restrict__ x, const float* __restrict__ wgt,
               float* __restrict__ out) {
  __shared__ float bufA[NDW];
  __shared__ float bufB[NDW];

  const int tid  = threadIdx.x;
  const int bid  = blockIdx.x;
  const int img  = bid >> 8;          // 0..15  (B*C)
  const int tile = bid & 255;         // 16x16 tiles
  const int ty   = (tile >> 4) * BT;
  const int tx   = (tile & 15) * BT;
  const int ch   = img & 1;

  const float* __restrict__ xin = x + (size_t)img * (IH * IW);

  // 5-point stencil weights (corners of the 3x3 are exactly 0.0)
  const float wN = wgt[ch * 9 + 1];
  const float wW = wgt[ch * 9 + 3];
  const float wC = wgt[ch * 9 + 4];
  const float wE = wgt[ch * 9 + 5];
  const float wS = wgt[ch * 9 + 7];

  // ---- global -> LDS (reflect-mapped), swizzled ----
  for (int i = tid; i < GY * GX; i += NT) {
    const int lr = i / GX;
    const int lc = i - lr * GX;
    int gr = ty - (HYW + 1) + lr;
    int gc = tx - (HXW + 4) + lc;
    gr = gr < 0 ? -gr : (gr >= IH ? 2 * IH - 2 - gr : gr);
    gc = gc < 0 ? -gc : (gc >= IW ? 2 * IW - 2 - gc : gc);
    const float v = xin[gr * IW + gc];
    const int s = swz(lr, lc);
    bufA[s] = v;
    bufB[s] = v;
  }
  __syncthreads();

  // thread -> work mapping: 16 x-groups of 8 cols, 32 row bands
  const int xg     = tid & 15;
  const int band   = tid >> 4;                          // 0..31
  const int nrows  = (band < 8) ? 4 : 3;                // 8*4 + 24*3 = 104 (wave-uniform)
  const int rstart = (band < 8) ? band * 4 : 32 + (band - 8) * 3;
  const int lc0    = 4 + xg * 8;                        // granule-aligned LDS col
  const int lane   = tid & 63;

  // mask is static across steps: build register copy from ORIGINAL values
  unsigned int m0[4], m1[4];
#pragma unroll
  for (int i = 0; i < 4; ++i) {
    const int rr = (i < nrows) ? (1 + rstart + i) : (1 + rstart);
    const float4 a = *(const float4*)&bufA[swz(rr, lc0)];
    const float4 b = *(const float4*)&bufA[swz(rr, lc0 + 4)];
    m0[i] = (a.x == 0.0f ? 0x000000FFu : 0u) | (a.y == 0.0f ? 0x0000FF00u : 0u)
          | (a.z == 0.0f ? 0x00FF0000u : 0u) | (a.w == 0.0f ? 0xFF000000u : 0u);
    m1[i] = (b.x == 0.0f ? 0x000000FFu : 0u) | (b.y == 0.0f ? 0x0000FF00u : 0u)
          | (b.z == 0.0f ? 0x00FF0000u : 0u) | (b.w == 0.0f ? 0xFF000000u : 0u);
  }

  auto step = [&](float* __restrict__ cu, float* __restrict__ nx) {
    const int r0 = 1 + rstart;
    float nn[8], cc[8], ss[8];
    {
      const float4 a = *(const float4*)&cu[swz(r0 - 1, lc0)];
      const float4 b = *(const float4*)&cu[swz(r0 - 1, lc0 + 4)];
      nn[0]=a.x; nn[1]=a.y; nn[2]=a.z; nn[3]=a.w;
      nn[4]=b.x; nn[5]=b.y; nn[6]=b.z; nn[7]=b.w;
      const float4 c_ = *(const float4*)&cu[swz(r0, lc0)];
      const float4 d_ = *(const float4*)&cu[swz(r0, lc0 + 4)];
      cc[0]=c_.x; cc[1]=c_.y; cc[2]=c_.z; cc[3]=c_.w;
      cc[4]=d_.x; cc[5]=d_.y; cc[6]=d_.z; cc[7]=d_.w;
    }
#pragma unroll
    for (int i = 0; i < 4; ++i) {
      if (i < nrows) {                       // wave-uniform
        const int r = r0 + i;
        {
          const float4 a = *(const float4*)&cu[swz(r + 1, lc0)];
          const float4 b = *(const float4*)&cu[swz(r + 1, lc0 + 4)];
          ss[0]=a.x; ss[1]=a.y; ss[2]=a.z; ss[3]=a.w;
          ss[4]=b.x; ss[5]=b.y; ss[6]=b.z; ss[7]=b.w;
        }
        // neighbor cols from adjacent lanes (conflict-free); edge lanes patch from LDS
        float cl = __shfl(cc[7], lane - 1, 64);
        float cr = __shfl(cc[0], lane + 1, 64);
        if (xg == 0)  cl = cu[swz(r, 3)];
        if (xg == 15) cr = cu[swz(r, 132)];
        float ov[8];
#pragma unroll
        for (int j = 0; j < 8; ++j) {
          const float l  = (j == 0) ? cl : cc[j - 1];
          const float r_ = (j == 7) ? cr : cc[j + 1];
          const float cv = fmaf(wC, cc[j],
                           fmaf(wW, l,
                           fmaf(wE, r_,
                           fmaf(wN, nn[j], wS * ss[j]))));
          const unsigned int mw = (j < 4) ? m0[i] : m1[i];
          const int sh = j & 3;
          const int mm = (int)(mw << ((3 - sh) * 8)) >> 24;  // sext byte -> 0 / -1
          const unsigned int rb = (__float_as_uint(cv) & (unsigned int)mm)
                                | (__float_as_uint(cc[j]) & ~(unsigned int)mm);
          ov[j] = __uint_as_float(rb);       // exact select: conv if hole else frozen x
        }
        float4 o0, o1;
        o0.x=ov[0]; o0.y=ov[1]; o0.z=ov[2]; o0.w=ov[3];
        o1.x=ov[4]; o1.y=ov[5]; o1.z=ov[6]; o1.w=ov[7];
        *(float4*)&nx[swz(r, lc0)]     = o0;
        *(float4*)&nx[swz(r, lc0 + 4)] = o1;
#pragma unroll
        for (int j = 0; j < 8; ++j) { nn[j] = cc[j]; cc[j] = ss[j]; }
      }
    }
  };

#pragma unroll 1
  for (int s = 0; s < TS; s += 2) {
    step(bufA, bufB);
    __syncthreads();
    step(bufB, bufA);
    __syncthreads();
  }

  // ---- store tile (result ends in bufA after an even number of steps) ----
  float* __restrict__ op = out + (size_t)img * (IH * IW);
#pragma unroll
  for (int i = tid; i < (BT * BT) / 4; i += NT) {   // 1024 float4 stores, 2 iters
    const int r  = i >> 4;
    const int c4 = (i & 15) * 4;
    const float4 v = *(const float4*)&bufA[swz(HYW + 1 + r, HXW + 4 + c4)];
    *(float4*)&op[(size_t)(ty + r) * IW + (tx + c4)] = v;
  }
}

extern "C" void kernel_launch(void* const* d_in, const int* in_sizes, int n_in,
                              void* d_out, int out_size, void* d_ws, size_t ws_size,
                              hipStream_t stream) {
  (void)in_sizes; (void)n_in; (void)d_ws; (void)ws_size; (void)out_size;
  const float* x   = (const float*)d_in[0];
  const float* wgt = (const float*)d_in[1];
  float* out       = (float*)d_out;
  // grid: 16 images (B*C) x 256 tiles (16x16) each
  hipLaunchKernelGGL(inpaint20, dim3(4096), dim3(NT), 0, stream, x, wgt, out);
}

// Round 3
// 286.565 us; speedup vs baseline: 2.6511x; 1.8184x over previous
//
#include <hip/hip_runtime.h>

#define IH 1024
#define IW 1024
#define GX 136        // region row stride in dwords (128 cols + 4 pad each side)
#define NT 512

// 16B-granule XOR swizzle.
//  - row term (((r>>3)^r)&7) spreads rows 2..16 apart into distinct classes
//  - col term ((c>>5)&1) fixes the xg-parity: within any 16-lane band the 8
//    granule positions are each hit exactly 2x (2-way = free, m136)
__device__ __forceinline__ int swz(int r, int c) {
  return (r * GX + c) ^ ((((r >> 3) ^ r) & 7) << 2) ^ (((c >> 5) & 1) << 2);
}

__device__ __forceinline__ int refl(int g, int n) {
  return g < 0 ? -g : (g >= n ? 2 * n - 2 - g : g);
}

// STEPS diffusion steps fully in LDS. GY = compute rows + 2 ghost rows.
// BTY x BTX = output tile. NRMAX = max rows per thread. MXF: mask from
// separate x pointer (pass 2) instead of from the loaded state (pass 1).
template<int STEPS, int GY, int BTY, int BTX, int NRMAX, bool MXF>
__device__ __forceinline__ void run(const float* __restrict__ in,
                                    const float* __restrict__ xm,
                                    const float* __restrict__ wgt,
                                    float* __restrict__ out,
                                    float* __restrict__ bufA,
                                    float* __restrict__ bufB) {
  constexpr int ROWS = GY - 2;                 // computed rows
  constexpr int YOFF = (ROWS - BTY) / 2 + 1;   // LDS row of output row 0
  constexpr int XOFF = (128 - BTX) / 2 + 4;    // LDS col of output col 0
  constexpr int TXT  = (IW + BTX - 1) / BTX;
  constexpr int TYT  = (IH + BTY - 1) / BTY;
  constexpr int TPI  = TXT * TYT;
  constexpr int BASE = ROWS / 32;              // band row schedule
  constexpr int REM  = ROWS - BASE * 32;       // multiple of 4 -> wave-uniform

  const int tid  = threadIdx.x;
  const int bid  = blockIdx.x;
  const int img  = bid / TPI;                  // 0..15 (B*C)
  const int tile = bid - img * TPI;
  const int tyi  = tile / TXT;
  const int ty   = tyi * BTY;
  const int tx   = (tile - tyi * TXT) * BTX;
  const int ch   = img & 1;

  const float* __restrict__ xin = in + (size_t)img * (IH * IW);

  // 5-point stencil weights (corners of the 3x3 are exactly 0.0)
  const float wN = wgt[ch * 9 + 1];
  const float wW = wgt[ch * 9 + 3];
  const float wC = wgt[ch * 9 + 4];
  const float wE = wgt[ch * 9 + 5];
  const float wS = wgt[ch * 9 + 7];

  // ---- global -> LDS (reflect-mapped), swizzled ----
  for (int i = tid; i < GY * GX; i += NT) {
    const int lr = i / GX;
    const int lc = i - lr * GX;
    const int gr = refl(ty - YOFF + lr, IH);
    const int gc = refl(tx - XOFF + lc, IW);
    const float v = xin[gr * IW + gc];
    const int s = swz(lr, lc);
    bufA[s] = v;
    bufB[s] = v;
  }
  __syncthreads();

  // thread -> work mapping: 16 x-groups of 8 cols, 32 row bands
  const int xg     = tid & 15;
  const int band   = tid >> 4;                 // 0..31
  const int nrows  = (band < REM) ? BASE + 1 : BASE;
  const int rstart = (band < REM) ? band * (BASE + 1)
                                  : REM * (BASE + 1) + (band - REM) * BASE;
  const int lc0    = 4 + xg * 8;               // granule-aligned LDS col
  const int lane   = tid & 63;

  // mask is static across steps: register copy, one byte per owned cell
  unsigned int m0[NRMAX], m1[NRMAX];
  if (MXF) {
    const float* __restrict__ xmi = xm + (size_t)img * (IH * IW);
#pragma unroll
    for (int i = 0; i < NRMAX; ++i) {
      const int ri = (i < nrows) ? i : (nrows - 1);
      const int gr = refl(ty - YOFF + 1 + rstart + ri, IH);
      const int gc0 = tx - XOFF + lc0;
      float v[8];
      if (gc0 >= 0 && gc0 + 7 < IW) {
        const float4 a = *(const float4*)&xmi[(size_t)gr * IW + gc0];
        const float4 b = *(const float4*)&xmi[(size_t)gr * IW + gc0 + 4];
        v[0]=a.x; v[1]=a.y; v[2]=a.z; v[3]=a.w;
        v[4]=b.x; v[5]=b.y; v[6]=b.z; v[7]=b.w;
      } else {
#pragma unroll
        for (int j = 0; j < 8; ++j) v[j] = xmi[(size_t)gr * IW + refl(gc0 + j, IW)];
      }
      m0[i] = (v[0]==0.0f?0x000000FFu:0u)|(v[1]==0.0f?0x0000FF00u:0u)
            | (v[2]==0.0f?0x00FF0000u:0u)|(v[3]==0.0f?0xFF000000u:0u);
      m1[i] = (v[4]==0.0f?0x000000FFu:0u)|(v[5]==0.0f?0x0000FF00u:0u)
            | (v[6]==0.0f?0x00FF0000u:0u)|(v[7]==0.0f?0xFF000000u:0u);
    }
  } else {
#pragma unroll
    for (int i = 0; i < NRMAX; ++i) {
      const int rr = (i < nrows) ? (1 + rstart + i) : (1 + rstart);
      const float4 a = *(const float4*)&bufA[swz(rr, lc0)];
      const float4 b = *(const float4*)&bufA[swz(rr, lc0 + 4)];
      m0[i] = (a.x==0.0f?0x000000FFu:0u)|(a.y==0.0f?0x0000FF00u:0u)
            | (a.z==0.0f?0x00FF0000u:0u)|(a.w==0.0f?0xFF000000u:0u);
      m1[i] = (b.x==0.0f?0x000000FFu:0u)|(b.y==0.0f?0x0000FF00u:0u)
            | (b.z==0.0f?0x00FF0000u:0u)|(b.w==0.0f?0xFF000000u:0u);
    }
  }

  auto step = [&](float* __restrict__ cu, float* __restrict__ nx) {
    const int r0 = 1 + rstart;
    float nn[8], cc[8], ss[8];
    {
      const float4 a = *(const float4*)&cu[swz(r0 - 1, lc0)];
      const float4 b = *(const float4*)&cu[swz(r0 - 1, lc0 + 4)];
      nn[0]=a.x; nn[1]=a.y; nn[2]=a.z; nn[3]=a.w;
      nn[4]=b.x; nn[5]=b.y; nn[6]=b.z; nn[7]=b.w;
      const float4 c_ = *(const float4*)&cu[swz(r0, lc0)];
      const float4 d_ = *(const float4*)&cu[swz(r0, lc0 + 4)];
      cc[0]=c_.x; cc[1]=c_.y; cc[2]=c_.z; cc[3]=c_.w;
      cc[4]=d_.x; cc[5]=d_.y; cc[6]=d_.z; cc[7]=d_.w;
    }
#pragma unroll
    for (int i = 0; i < NRMAX; ++i) {
      if (i < nrows) {                       // wave-uniform
        const int r = r0 + i;
        {
          const float4 a = *(const float4*)&cu[swz(r + 1, lc0)];
          const float4 b = *(const float4*)&cu[swz(r + 1, lc0 + 4)];
          ss[0]=a.x; ss[1]=a.y; ss[2]=a.z; ss[3]=a.w;
          ss[4]=b.x; ss[5]=b.y; ss[6]=b.z; ss[7]=b.w;
        }
        // neighbor cols from adjacent lanes (conflict-free); edges patch from LDS
        float cl = __shfl(cc[7], lane - 1, 64);
        float cr = __shfl(cc[0], lane + 1, 64);
        if (xg == 0)  cl = cu[swz(r, 3)];
        if (xg == 15) cr = cu[swz(r, 132)];
        float ov[8];
#pragma unroll
        for (int j = 0; j < 8; ++j) {
          const float l  = (j == 0) ? cl : cc[j - 1];
          const float r_ = (j == 7) ? cr : cc[j + 1];
          const float cv = fmaf(wC, cc[j],
                           fmaf(wW, l,
                           fmaf(wE, r_,
                           fmaf(wN, nn[j], wS * ss[j]))));
          const unsigned int mw = (j < 4) ? m0[i] : m1[i];
          const int sh = j & 3;
          const int mm = (int)(mw << ((3 - sh) * 8)) >> 24;  // sext byte -> 0 / -1
          const unsigned int rb = (__float_as_uint(cv) & (unsigned int)mm)
                                | (__float_as_uint(cc[j]) & ~(unsigned int)mm);
          ov[j] = __uint_as_float(rb);       // exact: conv if hole else frozen x
        }
        float4 o0, o1;
        o0.x=ov[0]; o0.y=ov[1]; o0.z=ov[2]; o0.w=ov[3];
        o1.x=ov[4]; o1.y=ov[5]; o1.z=ov[6]; o1.w=ov[7];
        *(float4*)&nx[swz(r, lc0)]     = o0;
        *(float4*)&nx[swz(r, lc0 + 4)] = o1;
#pragma unroll
        for (int j = 0; j < 8; ++j) { nn[j] = cc[j]; cc[j] = ss[j]; }
      }
    }
  };

#pragma unroll 1
  for (int s = 0; s < STEPS; s += 2) {
    step(bufA, bufB);
    __syncthreads();
    step(bufB, bufA);
    __syncthreads();
  }

  // ---- store tile (result in bufA after an even number of steps) ----
  float* __restrict__ op = out + (size_t)img * (IH * IW);
  constexpr int C4 = BTX / 4;
  for (int i = tid; i < BTY * C4; i += NT) {
    const int r  = i / C4;
    const int c4 = (i - r * C4) * 4;
    const int gr = ty + r;
    const int gc = tx + c4;
    if (gr < IH && gc + 3 < IW) {
      const float4 v = *(const float4*)&bufA[swz(YOFF + r, XOFF + c4)];
      *(float4*)&op[(size_t)gr * IW + gc] = v;
    }
  }
}

// Fallback: single kernel, 20 steps, 64x64 tile, 1 block/CU
__global__ __launch_bounds__(NT, 1)
void inpaint20(const float* __restrict__ x, const float* __restrict__ wgt,
               float* __restrict__ out) {
  __shared__ float A[14432], B[14432];   // 106*136 padded for swizzle
  run<20, 106, 64, 64, 4, false>(x, x, wgt, out, A, B);
}

// Two-pass: 10 steps each, 104x44 tile, region 128x64 (+2 ghost rows),
// LDS 2*8992*4 = 71.9 KB -> 2 blocks/CU
__global__ __launch_bounds__(NT, 4)
void inpaint10a(const float* __restrict__ x, const float* __restrict__ wgt,
                float* __restrict__ ws) {
  __shared__ float A[8992], B[8992];     // 66*136 padded for swizzle
  run<10, 66, 44, 104, 2, false>(x, x, wgt, ws, A, B);
}

__global__ __launch_bounds__(NT, 4)
void inpaint10b(const float* __restrict__ ws, const float* __restrict__ x,
                const float* __restrict__ wgt, float* __restrict__ out) {
  __shared__ float A[8992], B[8992];
  run<10, 66, 44, 104, 2, true>(ws, x, wgt, out, A, B);
}

extern "C" void kernel_launch(void* const* d_in, const int* in_sizes, int n_in,
                              void* d_out, int out_size, void* d_ws, size_t ws_size,
                              hipStream_t stream) {
  (void)in_sizes; (void)n_in; (void)out_size;
  const float* x   = (const float*)d_in[0];
  const float* wgt = (const float*)d_in[1];
  float* out       = (float*)d_out;
  const size_t need = (size_t)16 * IH * IW * sizeof(float);
  if (ws_size >= need) {
    float* ws = (float*)d_ws;
    // 16 imgs x (10 x-tiles * 24 y-tiles) = 3840 blocks
    hipLaunchKernelGGL(inpaint10a, dim3(3840), dim3(NT), 0, stream, x, wgt, ws);
    hipLaunchKernelGGL(inpaint10b, dim3(3840), dim3(NT), 0, stream, ws, x, wgt, out);
  } else {
    hipLaunchKernelGGL(inpaint20, dim3(4096), dim3(NT), 0, stream, x, wgt, out);
  }
}

// Round 4
// 185.761 us; speedup vs baseline: 4.0897x; 1.5427x over previous
//
#include <hip/hip_runtime.h>

#define IH 1024
#define IW 1024
#define NT 512
#define RPT 4            // rows per thread
#define NB 32            // bands (NT/16)
#define ROWS 128         // computed rows = NB*RPT
#define COLS 128         // computed cols = 16 xg * 8
#define PSTR 132         // boundary-plane stride (33 granules, == 1 mod 8 -> class rotation)

__device__ __forceinline__ int refl(int g, int n) {
  return g < 0 ? -g : (g >= n ? 2 * n - 2 - g : g);
}
// granule-parity fix: within a 16-lane band each of the 8 bank-granule classes
// is hit exactly 2x (2-way = free, m136)
__device__ __forceinline__ int pcol(int c) {
  return c ^ (((c >> 5) & 1) << 2);
}
__device__ __forceinline__ float dpp_shr1(float v) {  // lane i <- lane i-1 (16-lane row)
  return __int_as_float(__builtin_amdgcn_update_dpp(
      __float_as_int(v), __float_as_int(v), 0x111, 0xF, 0xF, false));
}
__device__ __forceinline__ float dpp_shl1(float v) {  // lane i <- lane i+1 (16-lane row)
  return __int_as_float(__builtin_amdgcn_update_dpp(
      __float_as_int(v), __float_as_int(v), 0x101, 0xF, 0xF, false));
}
__device__ __forceinline__ float bfi(unsigned int m, float a, float b) {
  return __uint_as_float((m & __float_as_uint(a)) | (~m & __float_as_uint(b)));
}

// STEPS diffusion steps; thread-strip state in registers, band boundaries via LDS.
// HALO >= STEPS+2 (static ghost ring contaminates output only after HALO+1 steps).
// MXF: mask from separate x pointer (pass 2) instead of the loaded state (pass 1).
template<int STEPS, int HALO, bool MXF>
__global__ __launch_bounds__(NT, 4)
void inpaintR(const float* __restrict__ in, const float* __restrict__ xm,
              const float* __restrict__ wgt, float* __restrict__ out) {
  // topA[p][b] = top row of band b (read by band b-1); topA[p][NB] = static south ghost
  // botA[p][b] = bottom row of band b-1 (read by band b); botA[p][0] = static north ghost
  __shared__ float topA[2][NB + 1][PSTR];
  __shared__ float botA[2][NB + 1][PSTR];

  constexpr int W   = 128 - 2 * HALO;          // output tile edge
  constexpr int TPD = (IW + W - 1) / W;        // tiles per dimension
  constexpr int TPI = TPD * TPD;

  const int tid = threadIdx.x;
  const int bid = blockIdx.x;
  const int img = bid / TPI;                   // 0..15 (B*C)
  const int t   = bid - img * TPI;
  const int ty  = (t / TPD) * W;
  const int tx  = (t % TPD) * W;
  const int ch  = img & 1;

  const float* __restrict__ xin = in + (size_t)img * (IH * IW);

  const float wN = wgt[ch * 9 + 1];
  const float wW = wgt[ch * 9 + 3];
  const float wC = wgt[ch * 9 + 4];
  const float wE = wgt[ch * 9 + 5];
  const float wS = wgt[ch * 9 + 7];

  const int xg   = tid & 15;
  const int band = tid >> 4;                   // 0..31
  const int r0   = band * RPT;                 // region row of thread's first row
  const int c0   = xg * 8;                     // region col of thread's first col
  const int gr0  = ty - HALO;                  // global row of region row 0
  const int gc0  = tx - HALO;                  // global col of region col 0

  auto load8 = [&](const float* __restrict__ p, int rr, float v[8]) {
    const float* rp = p + (size_t)refl(gr0 + rr, IH) * IW;
    const int gc = gc0 + c0;
    if (gc >= 0 && gc + 7 < IW) {
      const float4 a = *(const float4*)(rp + gc);
      const float4 b = *(const float4*)(rp + gc + 4);
      v[0]=a.x; v[1]=a.y; v[2]=a.z; v[3]=a.w;
      v[4]=b.x; v[5]=b.y; v[6]=b.z; v[7]=b.w;
    } else {
#pragma unroll
      for (int j = 0; j < 8; ++j) v[j] = rp[refl(gc + j, IW)];
    }
  };

  // ---- state strip + packed masks into registers ----
  float s[RPT][8];
  unsigned int mk[RPT][2];                     // mask byte per cell, bit7 = hole
#pragma unroll
  for (int i = 0; i < RPT; ++i) {
    load8(xin, r0 + i, s[i]);
    float mv[8];
    if (MXF) {
      load8(xm + (size_t)img * (IH * IW), r0 + i, mv);
    } else {
#pragma unroll
      for (int j = 0; j < 8; ++j) mv[j] = s[i][j];
    }
    mk[i][0] = (mv[0]==0.0f?0x80u:0u)       | (mv[1]==0.0f?0x8000u:0u)
             | (mv[2]==0.0f?0x800000u:0u)   | (mv[3]==0.0f?0x80000000u:0u);
    mk[i][1] = (mv[4]==0.0f?0x80u:0u)       | (mv[5]==0.0f?0x8000u:0u)
             | (mv[6]==0.0f?0x800000u:0u)   | (mv[7]==0.0f?0x80000000u:0u);
  }

  // ---- static ghost columns into registers (only xg 0 / 15 use them) ----
  float gle[RPT] = {0,0,0,0}, gre[RPT] = {0,0,0,0};
  if (xg == 0) {
    const int gc = refl(gc0 - 1, IW);
#pragma unroll
    for (int i = 0; i < RPT; ++i)
      gle[i] = xin[(size_t)refl(gr0 + r0 + i, IH) * IW + gc];
  }
  if (xg == 15) {
    const int gc = refl(gc0 + COLS, IW);
#pragma unroll
    for (int i = 0; i < RPT; ++i)
      gre[i] = xin[(size_t)refl(gr0 + r0 + i, IH) * IW + gc];
  }

  // ---- static ghost rows (both parities) + initial boundary planes ----
  if (band == 0) {
    float v[8]; load8(xin, -1, v);
    const float4 a = {v[0],v[1],v[2],v[3]};
    const float4 b = {v[4],v[5],v[6],v[7]};
#pragma unroll
    for (int h = 0; h < 2; ++h) {
      *(float4*)&botA[h][0][pcol(c0)]     = a;
      *(float4*)&botA[h][0][pcol(c0 + 4)] = b;
    }
  }
  if (band == NB - 1) {
    float v[8]; load8(xin, ROWS, v);
    const float4 a = {v[0],v[1],v[2],v[3]};
    const float4 b = {v[4],v[5],v[6],v[7]};
#pragma unroll
    for (int h = 0; h < 2; ++h) {
      *(float4*)&topA[h][NB][pcol(c0)]     = a;
      *(float4*)&topA[h][NB][pcol(c0 + 4)] = b;
    }
  }
  {
    const float4 t0 = {s[0][0], s[0][1], s[0][2], s[0][3]};
    const float4 t1 = {s[0][4], s[0][5], s[0][6], s[0][7]};
    *(float4*)&topA[0][band][pcol(c0)]     = t0;
    *(float4*)&topA[0][band][pcol(c0 + 4)] = t1;
    const float4 b0 = {s[RPT-1][0], s[RPT-1][1], s[RPT-1][2], s[RPT-1][3]};
    const float4 b1 = {s[RPT-1][4], s[RPT-1][5], s[RPT-1][6], s[RPT-1][7]};
    *(float4*)&botA[0][band + 1][pcol(c0)]     = b0;
    *(float4*)&botA[0][band + 1][pcol(c0 + 4)] = b1;
  }
  __syncthreads();

  // ---- time loop: all state in registers ----
  int par = 0;
#pragma unroll 1
  for (int st = 0; st < STEPS; ++st) {
    float nb[8], sb[8];
    {
      const float4 a = *(const float4*)&botA[par][band][pcol(c0)];
      const float4 b = *(const float4*)&botA[par][band][pcol(c0 + 4)];
      nb[0]=a.x; nb[1]=a.y; nb[2]=a.z; nb[3]=a.w;
      nb[4]=b.x; nb[5]=b.y; nb[6]=b.z; nb[7]=b.w;
      const float4 c = *(const float4*)&topA[par][band + 1][pcol(c0)];
      const float4 d = *(const float4*)&topA[par][band + 1][pcol(c0 + 4)];
      sb[0]=c.x; sb[1]=c.y; sb[2]=c.z; sb[3]=c.w;
      sb[4]=d.x; sb[5]=d.y; sb[6]=d.z; sb[7]=d.w;
    }
    float prev[8];
#pragma unroll
    for (int j = 0; j < 8; ++j) prev[j] = nb[j];
#pragma unroll
    for (int i = 0; i < RPT; ++i) {
      float cur[8];
#pragma unroll
      for (int j = 0; j < 8; ++j) cur[j] = s[i][j];
      float L = dpp_shr1(cur[7]);              // lane-1's col 7
      float R = dpp_shl1(cur[0]);              // lane+1's col 0
      if (xg == 0)  L = gle[i];                // static ghost col (cone-safe)
      if (xg == 15) R = gre[i];
#pragma unroll
      for (int j = 0; j < 8; ++j) {
        const float sth = (i < RPT - 1) ? s[i + 1][j] : sb[j];   // old south
        const float l  = j       ? cur[j - 1] : L;
        const float r_ = (j < 7) ? cur[j + 1] : R;
        const float cv = fmaf(wC, cur[j],
                         fmaf(wW, l,
                         fmaf(wE, r_,
                         fmaf(wN, prev[j], wS * sth))));
        const unsigned int mm =
            (unsigned int)(((int)(mk[i][j >> 2] << (24 - (j & 3) * 8))) >> 31);
        s[i][j] = bfi(mm, cv, cur[j]);         // exact: conv if hole else frozen
      }
#pragma unroll
      for (int j = 0; j < 8; ++j) prev[j] = cur[j];
    }
    // publish new boundary rows for neighbors (other parity)
    {
      const float4 t0 = {s[0][0], s[0][1], s[0][2], s[0][3]};
      const float4 t1 = {s[0][4], s[0][5], s[0][6], s[0][7]};
      *(float4*)&topA[par ^ 1][band][pcol(c0)]     = t0;
      *(float4*)&topA[par ^ 1][band][pcol(c0 + 4)] = t1;
      const float4 b0 = {s[RPT-1][0], s[RPT-1][1], s[RPT-1][2], s[RPT-1][3]};
      const float4 b1 = {s[RPT-1][4], s[RPT-1][5], s[RPT-1][6], s[RPT-1][7]};
      *(float4*)&botA[par ^ 1][band + 1][pcol(c0)]     = b0;
      *(float4*)&botA[par ^ 1][band + 1][pcol(c0 + 4)] = b1;
    }
    __syncthreads();
    par ^= 1;
  }

  // ---- store own cells inside the output window ----
  float* __restrict__ op = out + (size_t)img * (IH * IW);
#pragma unroll
  for (int i = 0; i < RPT; ++i) {
    const int rr = r0 + i;
    const int gr = gr0 + rr;
    if (rr >= HALO && rr < HALO + W && gr < IH) {
      if constexpr ((HALO & 3) == 0) {         // granule-aligned window: float4 stores
#pragma unroll
        for (int g = 0; g < 2; ++g) {
          const int cc = c0 + g * 4;
          const int gc = gc0 + cc;
          if (cc >= HALO && cc + 3 < HALO + W && gc + 3 < IW) {
            const float4 v = {s[i][g*4], s[i][g*4+1], s[i][g*4+2], s[i][g*4+3]};
            *(float4*)&op[(size_t)gr * IW + gc] = v;
          }
        }
      } else {
#pragma unroll
        for (int j = 0; j < 8; ++j) {
          const int cc = c0 + j;
          const int gc = gc0 + cc;
          if (cc >= HALO && cc < HALO + W && gc < IW)
            op[(size_t)gr * IW + gc] = s[i][j];
        }
      }
    }
  }
}

extern "C" void kernel_launch(void* const* d_in, const int* in_sizes, int n_in,
                              void* d_out, int out_size, void* d_ws, size_t ws_size,
                              hipStream_t stream) {
  (void)in_sizes; (void)n_in; (void)out_size;
  const float* x   = (const float*)d_in[0];
  const float* wgt = (const float*)d_in[1];
  float* out       = (float*)d_out;
  const size_t need = (size_t)16 * IH * IW * sizeof(float);
  if (ws_size >= need) {
    float* ws = (float*)d_ws;
    // two passes of 10 steps: halo 12, window 104, 10x10 tiles x 16 imgs = 1600
    inpaintR<10, 12, false><<<dim3(1600), dim3(NT), 0, stream>>>(x, x, wgt, ws);
    inpaintR<10, 12, true ><<<dim3(1600), dim3(NT), 0, stream>>>(ws, x, wgt, out);
  } else {
    // fallback: single 20-step pass, halo 22, window 84, 13x13 tiles x 16 imgs
    inpaintR<20, 22, false><<<dim3(16 * 13 * 13), dim3(NT), 0, stream>>>(x, x, wgt, out);
  }
}